// Round 14
// baseline (1675.941 us; speedup 1.0000x reference)
//
#include <hip/hip_runtime.h>
#include <hip/hip_bf16.h>

#define TT 4096
#define FF 80
#define HH 64
#define NB 128
#define LOG2E 1.44269504088896340736f
#define K2E   2.88539008177792681472f   // 2*log2(e)

// LDS byte layout (one block = one chain):
//   [0,128)     h buf par0 (64 bf16)
//   [128,256)   h buf par1
//   [256,448)   zero region (192 B) — A-operand rows 1..15 read here
//   [448 + wv*384 + par*192, +192)  per-wave x staging (96 bf16; 80..95 = 0)
#define LDS_ZERO 256
#define LDS_X    448
#define LDS_SIZE (448 + 4 * 384)   // 1984 B

using short8  = __attribute__((ext_vector_type(8))) short;   // 8 bf16 = 4 VGPR
using floatx4 = __attribute__((ext_vector_type(4))) float;

__device__ __forceinline__ unsigned short f2bf(float f) {    // RNE f32->bf16
    unsigned u = __builtin_bit_cast(unsigned, f);
    u += 0x7fffu + ((u >> 16) & 1u);
    return (unsigned short)(u >> 16);
}
__device__ __forceinline__ unsigned short cvt_bf16(float f) { // 1-instr convert
    unsigned r;
    asm("v_cvt_pk_bf16_f32 %0, %1, %2" : "=v"(r) : "v"(f), "v"(f));
    return (unsigned short)r;
}
__device__ __forceinline__ unsigned cvt_pk2(float a, float b) {
    unsigned r;
    asm("v_cvt_pk_bf16_f32 %0, %1, %2" : "=v"(r) : "v"(a), "v"(b));
    return r;
}
// LDS-visibility-only barrier: global loads stay in flight across it (r3+).
__device__ __forceinline__ void bar_lgkm() {
    asm volatile("s_waitcnt lgkmcnt(0)" ::: "memory");
    __builtin_amdgcn_s_barrier();
}
__device__ __forceinline__ floatx4 mfma16(short8 a, short8 b, floatx4 c) {
    return __builtin_amdgcn_mfma_f32_16x16x32_bf16(a, b, c, 0, 0, 0);
}
// activations on log2e-prescaled gates (r13, vetted)
__device__ __forceinline__ float sigm_s(float s) {
    return __builtin_amdgcn_rcpf(1.0f + __builtin_amdgcn_exp2f(-s));
}
__device__ __forceinline__ float tanh_s(float s) {
    return fmaf(-2.0f, __builtin_amdgcn_rcpf(1.0f + __builtin_amdgcn_exp2f(s + s)), 1.0f);
}

// ---------------------------------------------------------------------------
// FUSED LSTM (proj merged into scan): 256 blocks = 1 chain/CU, 4 waves.
// Per step s (critical path unchanged vs r13's 1148us scan):
//   barrier -> ds_read h A-frags -> 2 chained MFMA per gate with
//   C-in = xp(s) (x-partial + bias, precomputed LAST step) -> activation
//   (c2 = 2log2e*c domain) -> ds_write h -> barrier.
// Off the critical path, per step: compute xp(s+1) via 12 MFMAs (W_ih
// register-resident, K=80 padded to 96), stage x(s+2) reg->LDS (cvt_pk),
// and issue the global load of x(s+4) (distance-4 ring, lanes 0..19).
// This deletes the proj kernel, the PRE buffer (512MB) and its HBM
// round-trip (~185us of serialized wall time), and the 4 post-MFMA gate
// adds (PRE is now the MFMA C operand).
// ---------------------------------------------------------------------------
__global__ __launch_bounds__(256, 1)
void lstm_fused_mfma(const float* __restrict__ x,
                     const float* __restrict__ w_ih_f, const float* __restrict__ w_hh_f,
                     const float* __restrict__ b_ih_f, const float* __restrict__ b_hh_f,
                     const float* __restrict__ w_ih_b, const float* __restrict__ w_hh_b,
                     const float* __restrict__ b_ih_b, const float* __restrict__ b_hh_b,
                     float* __restrict__ h_out)        // [256][64]
{
    const int chain = blockIdx.x;       // dir*128 + bat
    const int dir   = chain >> 7;
    const int bat   = chain & (NB - 1);
    const int tid   = threadIdx.x;
    const int wv    = tid >> 6;         // unit window 16*wv..16*wv+15
    const int l     = tid & 63;
    const int b16   = l & 15;           // A row / C col
    const int g4    = l >> 4;           // k-group
    const bool actC = (g4 == 0);        // cell owners (lanes 0..15)
    const int  u    = 16 * wv + b16;

    const float* __restrict__ whh = dir ? w_hh_b : w_hh_f;
    const float* __restrict__ wih = dir ? w_ih_b : w_ih_f;
    const float* __restrict__ bi  = dir ? b_ih_b : b_ih_f;
    const float* __restrict__ bh  = dir ? b_hh_b : b_hh_f;

    // W_hh B-fragments (log2e-scaled): col n = gt*64+u, k = 32*kap+8*g4+j
    short8 Bh[4][2];
    #pragma unroll
    for (int gt = 0; gt < 4; ++gt) {
        const int n = gt * 64 + u;
        #pragma unroll
        for (int kap = 0; kap < 2; ++kap) {
            const float4 v0 = *reinterpret_cast<const float4*>(whh + n * HH + 32 * kap + 8 * g4);
            const float4 v1 = *reinterpret_cast<const float4*>(whh + n * HH + 32 * kap + 8 * g4 + 4);
            short8 s;
            s[0]=(short)f2bf(v0.x*LOG2E); s[1]=(short)f2bf(v0.y*LOG2E);
            s[2]=(short)f2bf(v0.z*LOG2E); s[3]=(short)f2bf(v0.w*LOG2E);
            s[4]=(short)f2bf(v1.x*LOG2E); s[5]=(short)f2bf(v1.y*LOG2E);
            s[6]=(short)f2bf(v1.z*LOG2E); s[7]=(short)f2bf(v1.w*LOG2E);
            Bh[gt][kap] = s;
        }
    }
    // W_ih B-fragments (log2e-scaled): k = 32*kx+8*g4+j, zero for k >= 80
    short8 Bx[4][3];
    floatx4 cinb[4];
    #pragma unroll
    for (int gt = 0; gt < 4; ++gt) {
        const int n = gt * 64 + u;
        const float bsum = (bi[n] + bh[n]) * LOG2E;
        cinb[gt] = (floatx4){bsum, bsum, bsum, bsum};
        #pragma unroll
        for (int kx = 0; kx < 3; ++kx) {
            const int f0 = 32 * kx + 8 * g4;
            short8 s;
            if (f0 < FF) {   // aligned: f0 in {0..72}, f0+7 <= 79
                const float4 v0 = *reinterpret_cast<const float4*>(wih + n * FF + f0);
                const float4 v1 = *reinterpret_cast<const float4*>(wih + n * FF + f0 + 4);
                s[0]=(short)f2bf(v0.x*LOG2E); s[1]=(short)f2bf(v0.y*LOG2E);
                s[2]=(short)f2bf(v0.z*LOG2E); s[3]=(short)f2bf(v0.w*LOG2E);
                s[4]=(short)f2bf(v1.x*LOG2E); s[5]=(short)f2bf(v1.y*LOG2E);
                s[6]=(short)f2bf(v1.z*LOG2E); s[7]=(short)f2bf(v1.w*LOG2E);
            } else {
                #pragma unroll
                for (int j = 0; j < 8; ++j) s[j] = 0;
            }
            Bx[gt][kx] = s;
        }
    }

    __shared__ __align__(16) char lds[LDS_SIZE];
    for (int i = tid; i < LDS_SIZE / 4; i += 256)
        reinterpret_cast<unsigned*>(lds)[i] = 0u;
    __syncthreads();   // zero-init visible before any staging write

    // x ring: lanes 0..19 of EVERY wave hold float4 x[te][4l..4l+3], depth 4.
    const float* __restrict__ xrow = x + (size_t)bat * (TT * FF);
    const bool lx = (l < 20);
    char* xsw = lds + LDS_X + wv * 384;   // own-wave staging base

    auto xaddr = [&](int s) {
        const int te = dir ? (TT - 1 - s) : s;
        return reinterpret_cast<const float4*>(xrow + (size_t)te * FF) + l;
    };
    float4 sl[4];
    const float4* pp[4];
    if (lx) {
        sl[0] = *xaddr(0); sl[1] = *xaddr(1); sl[2] = *xaddr(2); sl[3] = *xaddr(3);
    }
    pp[0] = xaddr(4); pp[1] = xaddr(5); pp[2] = xaddr(6); pp[3] = xaddr(7);
    const ptrdiff_t pst = dir ? -(4 * FF / 4) : (4 * FF / 4);   // float4 units / 4 steps

    // stage x(0) -> par0, x(1) -> par1
    if (lx) {
        *reinterpret_cast<uint2*>(xsw + 0 * 192 + 8 * l) =
            (uint2){cvt_pk2(sl[0].x, sl[0].y), cvt_pk2(sl[0].z, sl[0].w)};
        *reinterpret_cast<uint2*>(xsw + 1 * 192 + 8 * l) =
            (uint2){cvt_pk2(sl[1].x, sl[1].y), cvt_pk2(sl[1].z, sl[1].w)};
    }
    __syncthreads();

    floatx4 xp0, xp1, xp2, xp3;
#define XP_COMPUTE(PAR)                                                                       \
    {                                                                                         \
        const int xb = (b16 == 0 ? (LDS_X + wv * 384 + (PAR) * 192) : LDS_ZERO) + 16 * g4;    \
        const short8 X0 = *reinterpret_cast<const short8*>(lds + xb);                         \
        const short8 X1 = *reinterpret_cast<const short8*>(lds + xb + 64);                    \
        const short8 X2 = *reinterpret_cast<const short8*>(lds + xb + 128);                   \
        xp0 = mfma16(X2, Bx[0][2], mfma16(X1, Bx[0][1], mfma16(X0, Bx[0][0], cinb[0])));      \
        xp1 = mfma16(X2, Bx[1][2], mfma16(X1, Bx[1][1], mfma16(X0, Bx[1][0], cinb[1])));      \
        xp2 = mfma16(X2, Bx[2][2], mfma16(X1, Bx[2][1], mfma16(X0, Bx[2][0], cinb[2])));      \
        xp3 = mfma16(X2, Bx[3][2], mfma16(X1, Bx[3][1], mfma16(X0, Bx[3][0], cinb[3])));      \
    }
    XP_COMPUTE(0)   // xp(0) = x(0)*Wih + bias (all log2e-scaled)

    float c2 = 0.0f, h = 0.0f;   // c2 = 2*log2e * c

    #pragma unroll 1
    for (int t = 0; t < TT; t += 4) {
        const bool more = (t + 4 < TT);
        #pragma unroll
        for (int d = 0; d < 4; ++d) {
            const int cur = d & 1;   // (t+d)&1, t%4==0

            // ---- critical path: gates(s) = h(s)*Whh + xp(s) ----
            const int abase = (b16 == 0 ? 128 * cur : LDS_ZERO) + 16 * g4;
            const short8 A0 = *reinterpret_cast<const short8*>(lds + abase);
            const short8 A1 = *reinterpret_cast<const short8*>(lds + abase + 64);

            const floatx4 ci = mfma16(A1, Bh[0][1], mfma16(A0, Bh[0][0], xp0));
            const floatx4 cf = mfma16(A1, Bh[1][1], mfma16(A0, Bh[1][0], xp1));
            const floatx4 cg = mfma16(A1, Bh[2][1], mfma16(A0, Bh[2][0], xp2));
            const floatx4 co = mfma16(A1, Bh[3][1], mfma16(A0, Bh[3][0], xp3));

            // ---- shadow work: xp(s+1) from x staged at par cur^1 ----
            XP_COMPUTE(cur ^ 1)

            // ---- shadow work: ring rotate — stage x(s+2), load x(s+4) ----
            if (lx) {
                const float4 v = sl[(d + 2) & 3];
                *reinterpret_cast<uint2*>(xsw + cur * 192 + 8 * l) =
                    (uint2){cvt_pk2(v.x, v.y), cvt_pk2(v.z, v.w)};
                if (more) { sl[d] = *pp[d]; pp[d] += pst; }
            }

            // ---- cell update (lanes 0..15 of each wave) ----
            if (actC) {
                const float si = sigm_s(ci[0]);
                const float sf = sigm_s(cf[0]);
                const float tg = tanh_s(cg[0]);
                const float so = sigm_s(co[0]);
                c2 = fmaf(sf, c2, K2E * (si * tg));
                const float th = fmaf(-2.0f,
                    __builtin_amdgcn_rcpf(1.0f + __builtin_amdgcn_exp2f(c2)), 1.0f);
                h = so * th;
                *reinterpret_cast<unsigned short*>(lds + 128 * (cur ^ 1) + 2 * u) = cvt_bf16(h);
            }
            bar_lgkm();   // LDS visibility only; global ring stays in flight
        }
    }

    if (actC) h_out[(size_t)chain * HH + u] = h;
#undef XP_COMPUTE
}

// out[b][o] = b_fc[o] + h_fwd[b].w_fc[o][0:64] + h_bwd[b].w_fc[o][64:128]
__global__ __launch_bounds__(64, 1)
void fc_kernel(const float* __restrict__ h_out,   // [2][NB][HH]
               const float* __restrict__ w_fc,    // [8][128]
               const float* __restrict__ b_fc,    // [8]
               float* __restrict__ out)           // [NB][8]
{
    const int b = blockIdx.x;
    const int o = threadIdx.x;
    if (o < 8) {
        float acc = b_fc[o];
        #pragma unroll 4
        for (int j = 0; j < HH; ++j)
            acc = fmaf(h_out[(size_t)b * HH + j], w_fc[o * 128 + j], acc);
        #pragma unroll 4
        for (int j = 0; j < HH; ++j)
            acc = fmaf(h_out[(size_t)(NB + b) * HH + j], w_fc[o * 128 + 64 + j], acc);
        out[b * 8 + o] = acc;
    }
}

extern "C" void kernel_launch(void* const* d_in, const int* in_sizes, int n_in,
                              void* d_out, int out_size, void* d_ws, size_t ws_size,
                              hipStream_t stream) {
    const float* x      = (const float*)d_in[0];
    const float* w_ih_f = (const float*)d_in[2];
    const float* w_hh_f = (const float*)d_in[3];
    const float* b_ih_f = (const float*)d_in[4];
    const float* b_hh_f = (const float*)d_in[5];
    const float* w_ih_b = (const float*)d_in[6];
    const float* w_hh_b = (const float*)d_in[7];
    const float* b_ih_b = (const float*)d_in[8];
    const float* b_hh_b = (const float*)d_in[9];
    const float* w_fc   = (const float*)d_in[10];
    const float* b_fc   = (const float*)d_in[11];
    float* out   = (float*)d_out;
    float* h_out = (float*)d_ws;   // 2*128*64 f32 = 64 KiB (ws is far larger)

    lstm_fused_mfma<<<dim3(256), dim3(256), 0, stream>>>(
        x, w_ih_f, w_hh_f, b_ih_f, b_hh_f,
        w_ih_b, w_hh_b, b_ih_b, b_hh_b, h_out);

    fc_kernel<<<dim3(128), dim3(64), 0, stream>>>(h_out, w_fc, b_fc, out);
}

// Round 15
// 1413.209 us; speedup vs baseline: 1.1859x; 1.1859x over previous
//
#include <hip/hip_runtime.h>
#include <hip/hip_bf16.h>

#define TT 4096
#define FF 80
#define HH 64
#define NB 128
#define TB 256    // proj: timesteps per block
#define CT 8      // proj: timesteps per staging phase
#define XPAD 104  // proj LDS row stride in bf16 elems
#define LOG2E 1.44269504088896340736f
#define K2E   2.88539008177792681472f   // 2*log2(e)

using short8  = __attribute__((ext_vector_type(8))) short;   // 8 bf16 = 4 VGPR
using floatx4 = __attribute__((ext_vector_type(4))) float;

__device__ __forceinline__ float sigm(float x)  { return __builtin_amdgcn_rcpf(1.0f + __expf(-x)); }
__device__ __forceinline__ float tanh_f(float x){ return 1.0f - 2.0f * __builtin_amdgcn_rcpf(1.0f + __expf(2.0f * x)); }

__device__ __forceinline__ unsigned short f2bf(float f) {    // RNE f32->bf16
    unsigned u = __builtin_bit_cast(unsigned, f);
    u += 0x7fffu + ((u >> 16) & 1u);
    return (unsigned short)(u >> 16);
}
__device__ __forceinline__ float bflo(unsigned u) { return __builtin_bit_cast(float, u << 16); }
__device__ __forceinline__ float bfhi(unsigned u) { return __builtin_bit_cast(float, u & 0xffff0000u); }
__device__ __forceinline__ unsigned packbf2(float a, float b) {
    return (unsigned)f2bf(a) | ((unsigned)f2bf(b) << 16);
}

// single-instruction f32->bf16 (RNE) for the critical path
__device__ __forceinline__ unsigned short cvt_bf16(float f) {
    unsigned r;
    asm("v_cvt_pk_bf16_f32 %0, %1, %2" : "=v"(r) : "v"(f), "v"(f));
    return (unsigned short)r;
}

// LDS-visibility-only barrier: global loads stay in flight across it.
__device__ __forceinline__ void bar_lgkm() {
    asm volatile("s_waitcnt lgkmcnt(0)" ::: "memory");
    __builtin_amdgcn_s_barrier();
}

__device__ __forceinline__ floatx4 mfma16(short8 a, short8 b, floatx4 c) {
    return __builtin_amdgcn_mfma_f32_16x16x32_bf16(a, b, c, 0, 0, 0);
}

// activations on log2e-prescaled inputs (r13, vetted)
__device__ __forceinline__ float sigm_s(float s) {
    return __builtin_amdgcn_rcpf(1.0f + __builtin_amdgcn_exp2f(-s));
}
__device__ __forceinline__ float tanh_s(float s) {
    return fmaf(-2.0f, __builtin_amdgcn_rcpf(1.0f + __builtin_amdgcn_exp2f(s + s)), 1.0f);
}

// ---------------------------------------------------------------------------
// PROJ (MFMA): PRE[chain][t][unit*4 + gatetype] bf16, PRE-SCALED by log2e.
// Identical to round 13 (passed every round since r9).
// ---------------------------------------------------------------------------
__global__ __launch_bounds__(256, 1)
void lstm_proj_mfma(const float* __restrict__ x,
                    const float* __restrict__ w_ih_f, const float* __restrict__ b_ih_f,
                    const float* __restrict__ b_hh_f,
                    const float* __restrict__ w_ih_b, const float* __restrict__ b_ih_b,
                    const float* __restrict__ b_hh_b,
                    unsigned short* __restrict__ pre)
{
    const int blk   = blockIdx.x;
    const int ttile = blk & 15;
    const int dgrp  = blk >> 4;
    const int dir   = dgrp >> 3;
    const int bgrp  = dgrp & 7;
    const int tid   = threadIdx.x;
    const int wv    = tid >> 6;
    const int l     = tid & 63;
    const int b16   = l & 15;
    const int g     = l >> 4;
    const int t0    = ttile * TB;

    const float* __restrict__ wih = dir ? w_ih_b : w_ih_f;
    const float* __restrict__ bi  = dir ? b_ih_b : b_ih_f;
    const float* __restrict__ bh  = dir ? b_hh_b : b_hh_f;

    short8 Bf[4][3];
    float  bias[4];
    #pragma unroll
    for (int tp = 0; tp < 4; ++tp) {
        const int n = 64 * wv + 16 * tp + b16;
        bias[tp] = (bi[n] + bh[n]) * LOG2E;
        #pragma unroll
        for (int kap = 0; kap < 3; ++kap) {
            const int f0 = 32 * kap + 8 * g;
            float f[8];
            if (f0 < FF) {
                const float4 v0 = *reinterpret_cast<const float4*>(wih + n * FF + f0);
                const float4 v1 = *reinterpret_cast<const float4*>(wih + n * FF + f0 + 4);
                f[0]=v0.x; f[1]=v0.y; f[2]=v0.z; f[3]=v0.w;
                f[4]=v1.x; f[5]=v1.y; f[6]=v1.z; f[7]=v1.w;
            } else {
                #pragma unroll
                for (int j = 0; j < 8; ++j) f[j] = 0.0f;
            }
            short8 s;
            #pragma unroll
            for (int j = 0; j < 8; ++j) s[j] = (short)f2bf(f[j] * LOG2E);
            Bf[tp][kap] = s;
        }
    }

    __shared__ __align__(16) unsigned short xa[2][CT][16][XPAD];
    for (int i = tid; i < 2 * CT * 16 * XPAD / 2; i += 256)
        reinterpret_cast<unsigned*>(&xa[0][0][0][0])[i] = 0u;
    __syncthreads();

    const int nph = TB / CT;   // 32

    {   // prologue
        const int t0p = t0;
        const int te_base = dir ? (TT - CT - t0p) : t0p;
        float2 st[20];
        #pragma unroll
        for (int q = 0; q < 20; ++q) {
            const int i = q * 256 + tid;
            const int b = i / 320, r2 = i % 320;
            const int te_rel = r2 / 40, fq = r2 % 40;
            st[q] = *reinterpret_cast<const float2*>(
                x + ((size_t)(bgrp * 16 + b) * TT + te_base + te_rel) * FF + 2 * fq);
        }
        #pragma unroll
        for (int q = 0; q < 20; ++q) {
            const int i = q * 256 + tid;
            const int b = i / 320, r2 = i % 320;
            const int te_rel = r2 / 40, fq = r2 % 40;
            const int t_off = dir ? (CT - 1 - te_rel) : te_rel;
            *reinterpret_cast<unsigned*>(&xa[0][t_off][b][2 * fq]) = packbf2(st[q].x, st[q].y);
        }
    }
    __syncthreads();

    #pragma unroll 1
    for (int ph = 0; ph < nph; ++ph) {
        const int cur = ph & 1;
        const bool have = (ph + 1) < nph;

        float2 st[20];
        if (have) {
            const int t0p = t0 + (ph + 1) * CT;
            const int te_base = dir ? (TT - CT - t0p) : t0p;
            #pragma unroll
            for (int q = 0; q < 20; ++q) {
                const int i = q * 256 + tid;
                const int b = i / 320, r2 = i % 320;
                const int te_rel = r2 / 40, fq = r2 % 40;
                st[q] = *reinterpret_cast<const float2*>(
                    x + ((size_t)(bgrp * 16 + b) * TT + te_base + te_rel) * FF + 2 * fq);
            }
        }

        #pragma unroll
        for (int t_off = 0; t_off < CT; ++t_off) {
            short8 A[3];
            #pragma unroll
            for (int kap = 0; kap < 3; ++kap)
                A[kap] = *reinterpret_cast<const short8*>(&xa[cur][t_off][b16][32 * kap + 8 * g]);
            const int t = t0 + ph * CT + t_off;
            #pragma unroll
            for (int tp = 0; tp < 4; ++tp) {
                floatx4 acc = {bias[tp], bias[tp], bias[tp], bias[tp]};
                acc = mfma16(A[0], Bf[tp][0], acc);
                acc = mfma16(A[1], Bf[tp][1], acc);
                acc = mfma16(A[2], Bf[tp][2], acc);
                const int p = (16 * tp + b16) * 4 + wv;   // unit*4 + gatetype
                #pragma unroll
                for (int r = 0; r < 4; ++r) {
                    const int bb = dir * NB + bgrp * 16 + 4 * g + r;
                    pre[((size_t)bb * TT + t) * 256 + p] = f2bf(acc[r]);
                }
            }
        }

        if (have) {
            #pragma unroll
            for (int q = 0; q < 20; ++q) {
                const int i = q * 256 + tid;
                const int b = i / 320, r2 = i % 320;
                const int te_rel = r2 / 40, fq = r2 % 40;
                const int t_off = dir ? (CT - 1 - te_rel) : te_rel;
                *reinterpret_cast<unsigned*>(&xa[cur ^ 1][t_off][b][2 * fq]) = packbf2(st[q].x, st[q].y);
            }
        }
        bar_lgkm();
    }
}

// ---------------------------------------------------------------------------
// SCAN v9 = round-13 scan (measured best, 1148 us) + two isolated chain cuts:
//  1. PRE as MFMA C-in: pc decoded into {pre,0,0,0} while the A ds_read is in
//     flight (pc is register-resident, loaded 4 steps ago) -> deletes the 4
//     post-MFMA gate adds from the serial path. (r10's bundle regression is
//     now attributed to its exec-masked A-loads; this tests C-in isolated.)
//  2. c2-domain cell state (c2 = 2*log2e*c, vetted in r14's passing run):
//     removes the c*LOG2E mul from the h chain.
// Everything else byte-identical to r13: chained MFMA pair, zero-region A
// addressing, pointer-bump ring, one lgkm-only barrier per step.
// ---------------------------------------------------------------------------
__global__ __launch_bounds__(256, 1)
void lstm_scan_mfma6(const unsigned short* __restrict__ pre,  // [256][TT][256]
                     const float* __restrict__ w_hh_f, const float* __restrict__ w_hh_b,
                     float* __restrict__ h_out)               // [256][64]
{
    const int chain = blockIdx.x;       // dir*128 + bat
    const int dir   = chain >> 7;
    const int tid   = threadIdx.x;
    const int wv    = tid >> 6;         // unit window: 16*wv .. 16*wv+15
    const int l     = tid & 63;
    const int b16   = l & 15;           // A row / C col
    const int g4    = l >> 4;           // k-group
    const bool actC = (g4 == 0);        // C row-0 lanes (l = 0..15): cell owners
    const int  u    = 16 * wv + b16;    // this lane's unit (valid when actC)

    const float* __restrict__ whh = dir ? w_hh_b : w_hh_f;

    // B-fragments (scaled by log2e): gate gt (0:i 1:f 2:g 3:o), kap (K chunk).
    short8 Bf[4][2];
    #pragma unroll
    for (int gt = 0; gt < 4; ++gt) {
        const int n = gt * 64 + 16 * wv + b16;
        #pragma unroll
        for (int kap = 0; kap < 2; ++kap) {
            const float4 v0 = *reinterpret_cast<const float4*>(whh + n * HH + 32 * kap + 8 * g4);
            const float4 v1 = *reinterpret_cast<const float4*>(whh + n * HH + 32 * kap + 8 * g4 + 4);
            short8 s;
            s[0]=(short)f2bf(v0.x*LOG2E); s[1]=(short)f2bf(v0.y*LOG2E);
            s[2]=(short)f2bf(v0.z*LOG2E); s[3]=(short)f2bf(v0.w*LOG2E);
            s[4]=(short)f2bf(v1.x*LOG2E); s[5]=(short)f2bf(v1.y*LOG2E);
            s[6]=(short)f2bf(v1.z*LOG2E); s[7]=(short)f2bf(v1.w*LOG2E);
            Bf[gt][kap] = s;
        }
    }

    // LDS: bytes [0,128) = h buf0 (bf16[64]), [128,256) = h buf1,
    //      [256,384) = permanently-zero region (A rows 1-15 read here).
    __shared__ __align__(16) unsigned short hls[192];
    if (tid < 96) reinterpret_cast<unsigned*>(hls)[tid] = 0u;

    // PRE ring: actC lanes read uint2 = {i,f | g,o} bf16 at [chain][t][u*4].
    // 4 pre-offset pointers, each bumped +4*512B per ring cycle (no recompute).
    const uint2* __restrict__ prow = reinterpret_cast<const uint2*>(
        pre + (size_t)chain * TT * 256 + u * 4);
    uint2 prr[4] = {{0,0},{0,0},{0,0},{0,0}};
    const uint2* pp0 = prow + 4 * 64;
    const uint2* pp1 = prow + 5 * 64;
    const uint2* pp2 = prow + 6 * 64;
    const uint2* pp3 = prow + 7 * 64;
    if (actC) {
        prr[0] = prow[0 * 64];
        prr[1] = prow[1 * 64];
        prr[2] = prow[2 * 64];
        prr[3] = prow[3 * 64];
    }

    float c2 = 0.0f, h = 0.0f;   // c2 = 2*log2e * c
    __syncthreads();

    const char* lb = reinterpret_cast<const char*>(hls);
    char* lw = reinterpret_cast<char*>(hls);

    #pragma unroll 1
    for (int t = 0; t < TT; t += 4) {
        #pragma unroll
        for (int d = 0; d < 4; ++d) {
            const int cur = d & 1;       // (t+d)&1 since t%4==0

            // A fragments: row-0 lanes read h(t); others read zeros (r9/r13 layout).
            const int abase = (b16 == 0 ? 128 * cur : 256) + 16 * g4;
            const short8 A0 = *reinterpret_cast<const short8*>(lb + abase);
            const short8 A1 = *reinterpret_cast<const short8*>(lb + abase + 64);

            // capture PRE for this step, then reload ring slot (pointer bump).
            uint2 pc = prr[d];
            if (actC) {
                if (d == 0)      { prr[0] = *pp0; pp0 += 256; }
                else if (d == 1) { prr[1] = *pp1; pp1 += 256; }
                else if (d == 2) { prr[2] = *pp2; pp2 += 256; }
                else             { prr[3] = *pp3; pp3 += 256; }
            }

            // decode PRE into C-in while the A ds_read is in flight
            const floatx4 cin_i = {bflo(pc.x), 0.f, 0.f, 0.f};
            const floatx4 cin_f = {bfhi(pc.x), 0.f, 0.f, 0.f};
            const floatx4 cin_g = {bflo(pc.y), 0.f, 0.f, 0.f};
            const floatx4 cin_o = {bfhi(pc.y), 0.f, 0.f, 0.f};

            // G = h @ W_hh^T + PRE (chained MFMA pair, r13 form)
            const floatx4 ci = mfma16(A1, Bf[0][1], mfma16(A0, Bf[0][0], cin_i));
            const floatx4 cf = mfma16(A1, Bf[1][1], mfma16(A0, Bf[1][0], cin_f));
            const floatx4 cg = mfma16(A1, Bf[2][1], mfma16(A0, Bf[2][0], cin_g));
            const floatx4 co = mfma16(A1, Bf[3][1], mfma16(A0, Bf[3][0], cin_o));

            if (actC) {
                const float si = sigm_s(ci[0]);      // log2e-scaled gates
                const float sf = sigm_s(cf[0]);
                const float tg = tanh_s(cg[0]);
                const float so = sigm_s(co[0]);
                c2 = fmaf(sf, c2, K2E * (si * tg));  // c2 = 2log2e * c
                const float th = fmaf(-2.0f,
                    __builtin_amdgcn_rcpf(1.0f + __builtin_amdgcn_exp2f(c2)), 1.0f);
                h = so * th;
                *reinterpret_cast<unsigned short*>(lw + 128 * (cur ^ 1) + 2 * u) = cvt_bf16(h);
            }
            bar_lgkm();                  // LDS visibility only; ring stays in flight
        }
    }

    if (actC) h_out[(size_t)chain * HH + u] = h;
}

// ---------------------------------------------------------------------------
// Fallback: fully fused scan (round-1 kernel) if ws is too small for PRE.
// ---------------------------------------------------------------------------
__global__ __launch_bounds__(256, 1)
void lstm_scan_fused_kernel(const float* __restrict__ x,
                            const float* __restrict__ w_ih_f, const float* __restrict__ w_hh_f,
                            const float* __restrict__ b_ih_f, const float* __restrict__ b_hh_f,
                            const float* __restrict__ w_ih_b, const float* __restrict__ w_hh_b,
                            const float* __restrict__ b_ih_b, const float* __restrict__ b_hh_b,
                            float* __restrict__ h_out)
{
    const int blk = blockIdx.x;
    const int dir = blk >> 7;
    const int bat = blk & 127;
    const int tid = threadIdx.x;
    const int wv  = tid >> 6;
    const int ln  = tid & 63;

    const float* __restrict__ w_ih = dir ? w_ih_b : w_ih_f;
    const float* __restrict__ w_hh = dir ? w_hh_b : w_hh_f;
    const float* __restrict__ b_ih = dir ? b_ih_b : b_ih_f;
    const float* __restrict__ b_hh = dir ? b_hh_b : b_hh_f;

    float wi[FF], wh[HH];
    #pragma unroll
    for (int f = 0; f < FF; ++f) wi[f] = w_ih[tid * FF + f];
    #pragma unroll
    for (int j = 0; j < HH; ++j) wh[j] = w_hh[tid * HH + j];
    const float bias = b_ih[tid] + b_hh[tid];

    __shared__ float xs[2][FF];
    __shared__ float hbuf[4][HH];
    __shared__ float gbuf[2][256];

    const float* __restrict__ xrow = x + (size_t)bat * (TT * FF);
    float c = 0.0f, hreg = 0.0f;
    hbuf[wv][ln] = 0.0f;

    float xA = 0.0f;
    if (tid < FF) {
        xs[0][tid] = xrow[(size_t)(dir ? (TT - 1) : 0) * FF + tid];
        xA         = xrow[(size_t)(dir ? (TT - 2) : 1) * FF + tid];
    }
    __syncthreads();

    #pragma unroll 1
    for (int t = 0; t < TT; ++t) {
        const int cur = t & 1, nxt = cur ^ 1;
        float a0 = 0.f, a1 = 0.f, a2 = 0.f, a3 = 0.f;
        const float4* xs4 = reinterpret_cast<const float4*>(xs[cur]);
        #pragma unroll
        for (int f = 0; f < FF / 4; ++f) {
            float4 v = xs4[f];
            a0 = fmaf(wi[4*f+0], v.x, a0);
            a1 = fmaf(wi[4*f+1], v.y, a1);
            a2 = fmaf(wi[4*f+2], v.z, a2);
            a3 = fmaf(wi[4*f+3], v.w, a3);
        }
        const float4* hb4 = reinterpret_cast<const float4*>(hbuf[wv]);
        #pragma unroll
        for (int j = 0; j < HH / 4; ++j) {
            float4 v = hb4[j];
            a0 = fmaf(wh[4*j+0], v.x, a0);
            a1 = fmaf(wh[4*j+1], v.y, a1);
            a2 = fmaf(wh[4*j+2], v.z, a2);
            a3 = fmaf(wh[4*j+3], v.w, a3);
        }
        gbuf[cur][tid] = ((a0 + a1) + (a2 + a3)) + bias;

        if (tid < FF) {
            if (t + 1 < TT) xs[nxt][tid] = xA;
            if (t + 2 < TT) xA = xrow[(size_t)(dir ? (TT - 3 - t) : (t + 2)) * FF + tid];
        }
        __syncthreads();

        const float gi = gbuf[cur][ln];
        const float gf = gbuf[cur][64 + ln];
        const float gg = gbuf[cur][128 + ln];
        const float go = gbuf[cur][192 + ln];
        c    = sigm(gf) * c + sigm(gi) * tanh_f(gg);
        hreg = sigm(go) * tanh_f(c);
        hbuf[wv][ln] = hreg;
    }

    if (tid < HH) h_out[(size_t)(dir * 128 + bat) * HH + tid] = hreg;
}

__global__ __launch_bounds__(64, 1)
void fc_kernel(const float* __restrict__ h_out,   // [2][NB][HH]
               const float* __restrict__ w_fc,    // [8][128]
               const float* __restrict__ b_fc,    // [8]
               float* __restrict__ out)           // [NB][8]
{
    const int b = blockIdx.x;
    const int o = threadIdx.x;
    if (o < 8) {
        float acc = b_fc[o];
        #pragma unroll 4
        for (int j = 0; j < HH; ++j)
            acc = fmaf(h_out[(size_t)b * HH + j], w_fc[o * 128 + j], acc);
        #pragma unroll 4
        for (int j = 0; j < HH; ++j)
            acc = fmaf(h_out[(size_t)(NB + b) * HH + j], w_fc[o * 128 + 64 + j], acc);
        out[b * 8 + o] = acc;
    }
}

extern "C" void kernel_launch(void* const* d_in, const int* in_sizes, int n_in,
                              void* d_out, int out_size, void* d_ws, size_t ws_size,
                              hipStream_t stream) {
    const float* x      = (const float*)d_in[0];
    const float* w_ih_f = (const float*)d_in[2];
    const float* w_hh_f = (const float*)d_in[3];
    const float* b_ih_f = (const float*)d_in[4];
    const float* b_hh_f = (const float*)d_in[5];
    const float* w_ih_b = (const float*)d_in[6];
    const float* w_hh_b = (const float*)d_in[7];
    const float* b_ih_b = (const float*)d_in[8];
    const float* b_hh_b = (const float*)d_in[9];
    const float* w_fc   = (const float*)d_in[10];
    const float* b_fc   = (const float*)d_in[11];
    float* out = (float*)d_out;

    const size_t pre_bytes = (size_t)2 * NB * TT * 256 * 2;   // 512 MiB bf16
    const size_t need      = pre_bytes + 64 * 1024;

    if (ws_size >= need) {
        unsigned short* pre = (unsigned short*)d_ws;
        float* h_out = (float*)((char*)d_ws + pre_bytes);
        lstm_proj_mfma<<<dim3(256), dim3(256), 0, stream>>>(
            x, w_ih_f, b_ih_f, b_hh_f, w_ih_b, b_ih_b, b_hh_b, pre);
        lstm_scan_mfma6<<<dim3(256), dim3(256), 0, stream>>>(
            pre, w_hh_f, w_hh_b, h_out);
        fc_kernel<<<dim3(128), dim3(64), 0, stream>>>(h_out, w_fc, b_fc, out);
    } else {
        float* h_out = (float*)d_ws;   // 64 KiB
        lstm_scan_fused_kernel<<<dim3(256), dim3(256), 0, stream>>>(
            x, w_ih_f, w_hh_f, b_ih_f, b_hh_f,
            w_ih_b, w_hh_b, b_ih_b, b_hh_b, h_out);
        fc_kernel<<<dim3(128), dim3(64), 0, stream>>>(h_out, w_fc, b_fc, out);
    }
}

// Round 16
// 1411.986 us; speedup vs baseline: 1.1869x; 1.0009x over previous
//
#include <hip/hip_runtime.h>
#include <hip/hip_bf16.h>

#define TT 4096
#define FF 80
#define HH 64
#define NB 128
#define TB 256    // proj: timesteps per block
#define CT 8      // proj: timesteps per staging phase
#define XPAD 104  // proj LDS row stride in bf16 elems
#define LOG2E 1.44269504088896340736f
#define K2E   2.88539008177792681472f   // 2*log2(e)

using short8  = __attribute__((ext_vector_type(8))) short;   // 8 bf16 = 4 VGPR
using floatx4 = __attribute__((ext_vector_type(4))) float;

__device__ __forceinline__ float sigm(float x)  { return __builtin_amdgcn_rcpf(1.0f + __expf(-x)); }
__device__ __forceinline__ float tanh_f(float x){ return 1.0f - 2.0f * __builtin_amdgcn_rcpf(1.0f + __expf(2.0f * x)); }

__device__ __forceinline__ unsigned short f2bf(float f) {    // RNE f32->bf16
    unsigned u = __builtin_bit_cast(unsigned, f);
    u += 0x7fffu + ((u >> 16) & 1u);
    return (unsigned short)(u >> 16);
}
__device__ __forceinline__ float bflo(unsigned u) { return __builtin_bit_cast(float, u << 16); }
__device__ __forceinline__ float bfhi(unsigned u) { return __builtin_bit_cast(float, u & 0xffff0000u); }
__device__ __forceinline__ unsigned packbf2(float a, float b) {
    return (unsigned)f2bf(a) | ((unsigned)f2bf(b) << 16);
}

// single-instruction f32->bf16 (RNE) for the critical path
__device__ __forceinline__ unsigned short cvt_bf16(float f) {
    unsigned r;
    asm("v_cvt_pk_bf16_f32 %0, %1, %2" : "=v"(r) : "v"(f), "v"(f));
    return (unsigned short)r;
}

// LDS-visibility-only barrier: global loads stay in flight across it.
__device__ __forceinline__ void bar_lgkm() {
    asm volatile("s_waitcnt lgkmcnt(0)" ::: "memory");
    __builtin_amdgcn_s_barrier();
}

__device__ __forceinline__ floatx4 mfma16(short8 a, short8 b, floatx4 c) {
    return __builtin_amdgcn_mfma_f32_16x16x32_bf16(a, b, c, 0, 0, 0);
}

// activations on log2e-prescaled inputs (r13, vetted)
__device__ __forceinline__ float sigm_s(float s) {
    return __builtin_amdgcn_rcpf(1.0f + __builtin_amdgcn_exp2f(-s));
}
__device__ __forceinline__ float tanh_s(float s) {
    return fmaf(-2.0f, __builtin_amdgcn_rcpf(1.0f + __builtin_amdgcn_exp2f(s + s)), 1.0f);
}

// ---------------------------------------------------------------------------
// PROJ (MFMA): PRE[chain][t][unit*4 + gatetype] bf16, PRE-SCALED by log2e.
// Identical to round 13 (passed every round since r9).
// ---------------------------------------------------------------------------
__global__ __launch_bounds__(256, 1)
void lstm_proj_mfma(const float* __restrict__ x,
                    const float* __restrict__ w_ih_f, const float* __restrict__ b_ih_f,
                    const float* __restrict__ b_hh_f,
                    const float* __restrict__ w_ih_b, const float* __restrict__ b_ih_b,
                    const float* __restrict__ b_hh_b,
                    unsigned short* __restrict__ pre)
{
    const int blk   = blockIdx.x;
    const int ttile = blk & 15;
    const int dgrp  = blk >> 4;
    const int dir   = dgrp >> 3;
    const int bgrp  = dgrp & 7;
    const int tid   = threadIdx.x;
    const int wv    = tid >> 6;
    const int l     = tid & 63;
    const int b16   = l & 15;
    const int g     = l >> 4;
    const int t0    = ttile * TB;

    const float* __restrict__ wih = dir ? w_ih_b : w_ih_f;
    const float* __restrict__ bi  = dir ? b_ih_b : b_ih_f;
    const float* __restrict__ bh  = dir ? b_hh_b : b_hh_f;

    short8 Bf[4][3];
    float  bias[4];
    #pragma unroll
    for (int tp = 0; tp < 4; ++tp) {
        const int n = 64 * wv + 16 * tp + b16;
        bias[tp] = (bi[n] + bh[n]) * LOG2E;
        #pragma unroll
        for (int kap = 0; kap < 3; ++kap) {
            const int f0 = 32 * kap + 8 * g;
            float f[8];
            if (f0 < FF) {
                const float4 v0 = *reinterpret_cast<const float4*>(wih + n * FF + f0);
                const float4 v1 = *reinterpret_cast<const float4*>(wih + n * FF + f0 + 4);
                f[0]=v0.x; f[1]=v0.y; f[2]=v0.z; f[3]=v0.w;
                f[4]=v1.x; f[5]=v1.y; f[6]=v1.z; f[7]=v1.w;
            } else {
                #pragma unroll
                for (int j = 0; j < 8; ++j) f[j] = 0.0f;
            }
            short8 s;
            #pragma unroll
            for (int j = 0; j < 8; ++j) s[j] = (short)f2bf(f[j] * LOG2E);
            Bf[tp][kap] = s;
        }
    }

    __shared__ __align__(16) unsigned short xa[2][CT][16][XPAD];
    for (int i = tid; i < 2 * CT * 16 * XPAD / 2; i += 256)
        reinterpret_cast<unsigned*>(&xa[0][0][0][0])[i] = 0u;
    __syncthreads();

    const int nph = TB / CT;   // 32

    {   // prologue
        const int t0p = t0;
        const int te_base = dir ? (TT - CT - t0p) : t0p;
        float2 st[20];
        #pragma unroll
        for (int q = 0; q < 20; ++q) {
            const int i = q * 256 + tid;
            const int b = i / 320, r2 = i % 320;
            const int te_rel = r2 / 40, fq = r2 % 40;
            st[q] = *reinterpret_cast<const float2*>(
                x + ((size_t)(bgrp * 16 + b) * TT + te_base + te_rel) * FF + 2 * fq);
        }
        #pragma unroll
        for (int q = 0; q < 20; ++q) {
            const int i = q * 256 + tid;
            const int b = i / 320, r2 = i % 320;
            const int te_rel = r2 / 40, fq = r2 % 40;
            const int t_off = dir ? (CT - 1 - te_rel) : te_rel;
            *reinterpret_cast<unsigned*>(&xa[0][t_off][b][2 * fq]) = packbf2(st[q].x, st[q].y);
        }
    }
    __syncthreads();

    #pragma unroll 1
    for (int ph = 0; ph < nph; ++ph) {
        const int cur = ph & 1;
        const bool have = (ph + 1) < nph;

        float2 st[20];
        if (have) {
            const int t0p = t0 + (ph + 1) * CT;
            const int te_base = dir ? (TT - CT - t0p) : t0p;
            #pragma unroll
            for (int q = 0; q < 20; ++q) {
                const int i = q * 256 + tid;
                const int b = i / 320, r2 = i % 320;
                const int te_rel = r2 / 40, fq = r2 % 40;
                st[q] = *reinterpret_cast<const float2*>(
                    x + ((size_t)(bgrp * 16 + b) * TT + te_base + te_rel) * FF + 2 * fq);
            }
        }

        #pragma unroll
        for (int t_off = 0; t_off < CT; ++t_off) {
            short8 A[3];
            #pragma unroll
            for (int kap = 0; kap < 3; ++kap)
                A[kap] = *reinterpret_cast<const short8*>(&xa[cur][t_off][b16][32 * kap + 8 * g]);
            const int t = t0 + ph * CT + t_off;
            #pragma unroll
            for (int tp = 0; tp < 4; ++tp) {
                floatx4 acc = {bias[tp], bias[tp], bias[tp], bias[tp]};
                acc = mfma16(A[0], Bf[tp][0], acc);
                acc = mfma16(A[1], Bf[tp][1], acc);
                acc = mfma16(A[2], Bf[tp][2], acc);
                const int p = (16 * tp + b16) * 4 + wv;   // unit*4 + gatetype
                #pragma unroll
                for (int r = 0; r < 4; ++r) {
                    const int bb = dir * NB + bgrp * 16 + 4 * g + r;
                    pre[((size_t)bb * TT + t) * 256 + p] = f2bf(acc[r]);
                }
            }
        }

        if (have) {
            #pragma unroll
            for (int q = 0; q < 20; ++q) {
                const int i = q * 256 + tid;
                const int b = i / 320, r2 = i % 320;
                const int te_rel = r2 / 40, fq = r2 % 40;
                const int t_off = dir ? (CT - 1 - te_rel) : te_rel;
                *reinterpret_cast<unsigned*>(&xa[cur ^ 1][t_off][b][2 * fq]) = packbf2(st[q].x, st[q].y);
            }
        }
        bar_lgkm();
    }
}

// ---------------------------------------------------------------------------
// SCAN v9 = round-13 scan (measured best, 1148 us) + two isolated chain cuts:
//  1. PRE as MFMA C-in: pc decoded into {pre,0,0,0} while the A ds_read is in
//     flight (pc is register-resident, loaded 4 steps ago) -> deletes the 4
//     post-MFMA gate adds from the serial path. (r10's bundle regression is
//     now attributed to its exec-masked A-loads; this tests C-in isolated.)
//  2. c2-domain cell state (c2 = 2*log2e*c, vetted in r14's passing run):
//     removes the c*LOG2E mul from the h chain.
// Everything else byte-identical to r13: chained MFMA pair, zero-region A
// addressing, pointer-bump ring, one lgkm-only barrier per step.
// ---------------------------------------------------------------------------
__global__ __launch_bounds__(256, 1)
void lstm_scan_mfma6(const unsigned short* __restrict__ pre,  // [256][TT][256]
                     const float* __restrict__ w_hh_f, const float* __restrict__ w_hh_b,
                     float* __restrict__ h_out)               // [256][64]
{
    const int chain = blockIdx.x;       // dir*128 + bat
    const int dir   = chain >> 7;
    const int tid   = threadIdx.x;
    const int wv    = tid >> 6;         // unit window: 16*wv .. 16*wv+15
    const int l     = tid & 63;
    const int b16   = l & 15;           // A row / C col
    const int g4    = l >> 4;           // k-group
    const bool actC = (g4 == 0);        // C row-0 lanes (l = 0..15): cell owners
    const int  u    = 16 * wv + b16;    // this lane's unit (valid when actC)

    const float* __restrict__ whh = dir ? w_hh_b : w_hh_f;

    // B-fragments (scaled by log2e): gate gt (0:i 1:f 2:g 3:o), kap (K chunk).
    short8 Bf[4][2];
    #pragma unroll
    for (int gt = 0; gt < 4; ++gt) {
        const int n = gt * 64 + 16 * wv + b16;
        #pragma unroll
        for (int kap = 0; kap < 2; ++kap) {
            const float4 v0 = *reinterpret_cast<const float4*>(whh + n * HH + 32 * kap + 8 * g4);
            const float4 v1 = *reinterpret_cast<const float4*>(whh + n * HH + 32 * kap + 8 * g4 + 4);
            short8 s;
            s[0]=(short)f2bf(v0.x*LOG2E); s[1]=(short)f2bf(v0.y*LOG2E);
            s[2]=(short)f2bf(v0.z*LOG2E); s[3]=(short)f2bf(v0.w*LOG2E);
            s[4]=(short)f2bf(v1.x*LOG2E); s[5]=(short)f2bf(v1.y*LOG2E);
            s[6]=(short)f2bf(v1.z*LOG2E); s[7]=(short)f2bf(v1.w*LOG2E);
            Bf[gt][kap] = s;
        }
    }

    // LDS: bytes [0,128) = h buf0 (bf16[64]), [128,256) = h buf1,
    //      [256,384) = permanently-zero region (A rows 1-15 read here).
    __shared__ __align__(16) unsigned short hls[192];
    if (tid < 96) reinterpret_cast<unsigned*>(hls)[tid] = 0u;

    // PRE ring: actC lanes read uint2 = {i,f | g,o} bf16 at [chain][t][u*4].
    // 4 pre-offset pointers, each bumped +4*512B per ring cycle (no recompute).
    const uint2* __restrict__ prow = reinterpret_cast<const uint2*>(
        pre + (size_t)chain * TT * 256 + u * 4);
    uint2 prr[4] = {{0,0},{0,0},{0,0},{0,0}};
    const uint2* pp0 = prow + 4 * 64;
    const uint2* pp1 = prow + 5 * 64;
    const uint2* pp2 = prow + 6 * 64;
    const uint2* pp3 = prow + 7 * 64;
    if (actC) {
        prr[0] = prow[0 * 64];
        prr[1] = prow[1 * 64];
        prr[2] = prow[2 * 64];
        prr[3] = prow[3 * 64];
    }

    float c2 = 0.0f, h = 0.0f;   // c2 = 2*log2e * c
    __syncthreads();

    const char* lb = reinterpret_cast<const char*>(hls);
    char* lw = reinterpret_cast<char*>(hls);

    #pragma unroll 1
    for (int t = 0; t < TT; t += 4) {
        #pragma unroll
        for (int d = 0; d < 4; ++d) {
            const int cur = d & 1;       // (t+d)&1 since t%4==0

            // A fragments: row-0 lanes read h(t); others read zeros (r9/r13 layout).
            const int abase = (b16 == 0 ? 128 * cur : 256) + 16 * g4;
            const short8 A0 = *reinterpret_cast<const short8*>(lb + abase);
            const short8 A1 = *reinterpret_cast<const short8*>(lb + abase + 64);

            // capture PRE for this step, then reload ring slot (pointer bump).
            uint2 pc = prr[d];
            if (actC) {
                if (d == 0)      { prr[0] = *pp0; pp0 += 256; }
                else if (d == 1) { prr[1] = *pp1; pp1 += 256; }
                else if (d == 2) { prr[2] = *pp2; pp2 += 256; }
                else             { prr[3] = *pp3; pp3 += 256; }
            }

            // decode PRE into C-in while the A ds_read is in flight
            const floatx4 cin_i = {bflo(pc.x), 0.f, 0.f, 0.f};
            const floatx4 cin_f = {bfhi(pc.x), 0.f, 0.f, 0.f};
            const floatx4 cin_g = {bflo(pc.y), 0.f, 0.f, 0.f};
            const floatx4 cin_o = {bfhi(pc.y), 0.f, 0.f, 0.f};

            // G = h @ W_hh^T + PRE (chained MFMA pair, r13 form)
            const floatx4 ci = mfma16(A1, Bf[0][1], mfma16(A0, Bf[0][0], cin_i));
            const floatx4 cf = mfma16(A1, Bf[1][1], mfma16(A0, Bf[1][0], cin_f));
            const floatx4 cg = mfma16(A1, Bf[2][1], mfma16(A0, Bf[2][0], cin_g));
            const floatx4 co = mfma16(A1, Bf[3][1], mfma16(A0, Bf[3][0], cin_o));

            if (actC) {
                const float si = sigm_s(ci[0]);      // log2e-scaled gates
                const float sf = sigm_s(cf[0]);
                const float tg = tanh_s(cg[0]);
                const float so = sigm_s(co[0]);
                c2 = fmaf(sf, c2, K2E * (si * tg));  // c2 = 2log2e * c
                const float th = fmaf(-2.0f,
                    __builtin_amdgcn_rcpf(1.0f + __builtin_amdgcn_exp2f(c2)), 1.0f);
                h = so * th;
                *reinterpret_cast<unsigned short*>(lw + 128 * (cur ^ 1) + 2 * u) = cvt_bf16(h);
            }
            bar_lgkm();                  // LDS visibility only; ring stays in flight
        }
    }

    if (actC) h_out[(size_t)chain * HH + u] = h;
}

// ---------------------------------------------------------------------------
// Fallback: fully fused scan (round-1 kernel) if ws is too small for PRE.
// ---------------------------------------------------------------------------
__global__ __launch_bounds__(256, 1)
void lstm_scan_fused_kernel(const float* __restrict__ x,
                            const float* __restrict__ w_ih_f, const float* __restrict__ w_hh_f,
                            const float* __restrict__ b_ih_f, const float* __restrict__ b_hh_f,
                            const float* __restrict__ w_ih_b, const float* __restrict__ w_hh_b,
                            const float* __restrict__ b_ih_b, const float* __restrict__ b_hh_b,
                            float* __restrict__ h_out)
{
    const int blk = blockIdx.x;
    const int dir = blk >> 7;
    const int bat = blk & 127;
    const int tid = threadIdx.x;
    const int wv  = tid >> 6;
    const int ln  = tid & 63;

    const float* __restrict__ w_ih = dir ? w_ih_b : w_ih_f;
    const float* __restrict__ w_hh = dir ? w_hh_b : w_hh_f;
    const float* __restrict__ b_ih = dir ? b_ih_b : b_ih_f;
    const float* __restrict__ b_hh = dir ? b_hh_b : b_hh_f;

    float wi[FF], wh[HH];
    #pragma unroll
    for (int f = 0; f < FF; ++f) wi[f] = w_ih[tid * FF + f];
    #pragma unroll
    for (int j = 0; j < HH; ++j) wh[j] = w_hh[tid * HH + j];
    const float bias = b_ih[tid] + b_hh[tid];

    __shared__ float xs[2][FF];
    __shared__ float hbuf[4][HH];
    __shared__ float gbuf[2][256];

    const float* __restrict__ xrow = x + (size_t)bat * (TT * FF);
    float c = 0.0f, hreg = 0.0f;
    hbuf[wv][ln] = 0.0f;

    float xA = 0.0f;
    if (tid < FF) {
        xs[0][tid] = xrow[(size_t)(dir ? (TT - 1) : 0) * FF + tid];
        xA         = xrow[(size_t)(dir ? (TT - 2) : 1) * FF + tid];
    }
    __syncthreads();

    #pragma unroll 1
    for (int t = 0; t < TT; ++t) {
        const int cur = t & 1, nxt = cur ^ 1;
        float a0 = 0.f, a1 = 0.f, a2 = 0.f, a3 = 0.f;
        const float4* xs4 = reinterpret_cast<const float4*>(xs[cur]);
        #pragma unroll
        for (int f = 0; f < FF / 4; ++f) {
            float4 v = xs4[f];
            a0 = fmaf(wi[4*f+0], v.x, a0);
            a1 = fmaf(wi[4*f+1], v.y, a1);
            a2 = fmaf(wi[4*f+2], v.z, a2);
            a3 = fmaf(wi[4*f+3], v.w, a3);
        }
        const float4* hb4 = reinterpret_cast<const float4*>(hbuf[wv]);
        #pragma unroll
        for (int j = 0; j < HH / 4; ++j) {
            float4 v = hb4[j];
            a0 = fmaf(wh[4*j+0], v.x, a0);
            a1 = fmaf(wh[4*j+1], v.y, a1);
            a2 = fmaf(wh[4*j+2], v.z, a2);
            a3 = fmaf(wh[4*j+3], v.w, a3);
        }
        gbuf[cur][tid] = ((a0 + a1) + (a2 + a3)) + bias;

        if (tid < FF) {
            if (t + 1 < TT) xs[nxt][tid] = xA;
            if (t + 2 < TT) xA = xrow[(size_t)(dir ? (TT - 3 - t) : (t + 2)) * FF + tid];
        }
        __syncthreads();

        const float gi = gbuf[cur][ln];
        const float gf = gbuf[cur][64 + ln];
        const float gg = gbuf[cur][128 + ln];
        const float go = gbuf[cur][192 + ln];
        c    = sigm(gf) * c + sigm(gi) * tanh_f(gg);
        hreg = sigm(go) * tanh_f(c);
        hbuf[wv][ln] = hreg;
    }

    if (tid < HH) h_out[(size_t)(dir * 128 + bat) * HH + tid] = hreg;
}

__global__ __launch_bounds__(64, 1)
void fc_kernel(const float* __restrict__ h_out,   // [2][NB][HH]
               const float* __restrict__ w_fc,    // [8][128]
               const float* __restrict__ b_fc,    // [8]
               float* __restrict__ out)           // [NB][8]
{
    const int b = blockIdx.x;
    const int o = threadIdx.x;
    if (o < 8) {
        float acc = b_fc[o];
        #pragma unroll 4
        for (int j = 0; j < HH; ++j)
            acc = fmaf(h_out[(size_t)b * HH + j], w_fc[o * 128 + j], acc);
        #pragma unroll 4
        for (int j = 0; j < HH; ++j)
            acc = fmaf(h_out[(size_t)(NB + b) * HH + j], w_fc[o * 128 + 64 + j], acc);
        out[b * 8 + o] = acc;
    }
}

extern "C" void kernel_launch(void* const* d_in, const int* in_sizes, int n_in,
                              void* d_out, int out_size, void* d_ws, size_t ws_size,
                              hipStream_t stream) {
    const float* x      = (const float*)d_in[0];
    const float* w_ih_f = (const float*)d_in[2];
    const float* w_hh_f = (const float*)d_in[3];
    const float* b_ih_f = (const float*)d_in[4];
    const float* b_hh_f = (const float*)d_in[5];
    const float* w_ih_b = (const float*)d_in[6];
    const float* w_hh_b = (const float*)d_in[7];
    const float* b_ih_b = (const float*)d_in[8];
    const float* b_hh_b = (const float*)d_in[9];
    const float* w_fc   = (const float*)d_in[10];
    const float* b_fc   = (const float*)d_in[11];
    float* out = (float*)d_out;

    const size_t pre_bytes = (size_t)2 * NB * TT * 256 * 2;   // 512 MiB bf16
    const size_t need      = pre_bytes + 64 * 1024;

    if (ws_size >= need) {
        unsigned short* pre = (unsigned short*)d_ws;
        float* h_out = (float*)((char*)d_ws + pre_bytes);
        lstm_proj_mfma<<<dim3(256), dim3(256), 0, stream>>>(
            x, w_ih_f, b_ih_f, b_hh_f, w_ih_b, b_ih_b, b_hh_b, pre);
        lstm_scan_mfma6<<<dim3(256), dim3(256), 0, stream>>>(
            pre, w_hh_f, w_hh_b, h_out);
        fc_kernel<<<dim3(128), dim3(64), 0, stream>>>(h_out, w_fc, b_fc, out);
    } else {
        float* h_out = (float*)d_ws;   // 64 KiB
        lstm_scan_fused_kernel<<<dim3(256), dim3(256), 0, stream>>>(
            x, w_ih_f, w_hh_f, b_ih_f, b_hh_f,
            w_ih_b, w_hh_b, b_ih_b, b_hh_b, h_out);
        fc_kernel<<<dim3(128), dim3(64), 0, stream>>>(h_out, w_fc, b_fc, out);
    }
}

// Round 17
// 1326.357 us; speedup vs baseline: 1.2636x; 1.0646x over previous
//
#include <hip/hip_runtime.h>
#include <hip/hip_bf16.h>

#define TT 4096
#define FF 80
#define HH 64
#define NB 128
#define TB 256    // proj: timesteps per block
#define CT 8      // proj: timesteps per staging phase
#define XPAD 104  // proj LDS row stride in bf16 elems
#define LOG2E 1.44269504088896340736f
#define K2E   2.88539008177792681472f   // 2*log2(e)

using short8  = __attribute__((ext_vector_type(8))) short;   // 8 bf16 = 4 VGPR
using floatx4 = __attribute__((ext_vector_type(4))) float;

__device__ __forceinline__ float sigm(float x)  { return __builtin_amdgcn_rcpf(1.0f + __expf(-x)); }
__device__ __forceinline__ float tanh_f(float x){ return 1.0f - 2.0f * __builtin_amdgcn_rcpf(1.0f + __expf(2.0f * x)); }

__device__ __forceinline__ unsigned short f2bf(float f) {    // RNE f32->bf16
    unsigned u = __builtin_bit_cast(unsigned, f);
    u += 0x7fffu + ((u >> 16) & 1u);
    return (unsigned short)(u >> 16);
}
__device__ __forceinline__ float bflo(unsigned u) { return __builtin_bit_cast(float, u << 16); }
__device__ __forceinline__ float bfhi(unsigned u) { return __builtin_bit_cast(float, u & 0xffff0000u); }
__device__ __forceinline__ unsigned packbf2(float a, float b) {
    return (unsigned)f2bf(a) | ((unsigned)f2bf(b) << 16);
}

// single-instruction f32->bf16 (RNE) for the critical path
__device__ __forceinline__ unsigned short cvt_bf16(float f) {
    unsigned r;
    asm("v_cvt_pk_bf16_f32 %0, %1, %2" : "=v"(r) : "v"(f), "v"(f));
    return (unsigned short)r;
}

// LDS-visibility-only barrier: global loads stay in flight across it.
__device__ __forceinline__ void bar_lgkm() {
    asm volatile("s_waitcnt lgkmcnt(0)" ::: "memory");
    __builtin_amdgcn_s_barrier();
}

__device__ __forceinline__ floatx4 mfma16(short8 a, short8 b, floatx4 c) {
    return __builtin_amdgcn_mfma_f32_16x16x32_bf16(a, b, c, 0, 0, 0);
}

// activations on log2e-prescaled inputs (r13, vetted)
__device__ __forceinline__ float sigm_s(float s) {
    return __builtin_amdgcn_rcpf(1.0f + __builtin_amdgcn_exp2f(-s));
}
__device__ __forceinline__ float tanh_s(float s) {
    return fmaf(-2.0f, __builtin_amdgcn_rcpf(1.0f + __builtin_amdgcn_exp2f(s + s)), 1.0f);
}

// ---------------------------------------------------------------------------
// PROJ (MFMA): PRE[chain][t][unit*4 + gatetype] bf16, PRE-SCALED by log2e.
// Identical to round 13 (passed every round since r9).
// ---------------------------------------------------------------------------
__global__ __launch_bounds__(256, 1)
void lstm_proj_mfma(const float* __restrict__ x,
                    const float* __restrict__ w_ih_f, const float* __restrict__ b_ih_f,
                    const float* __restrict__ b_hh_f,
                    const float* __restrict__ w_ih_b, const float* __restrict__ b_ih_b,
                    const float* __restrict__ b_hh_b,
                    unsigned short* __restrict__ pre)
{
    const int blk   = blockIdx.x;
    const int ttile = blk & 15;
    const int dgrp  = blk >> 4;
    const int dir   = dgrp >> 3;
    const int bgrp  = dgrp & 7;
    const int tid   = threadIdx.x;
    const int wv    = tid >> 6;
    const int l     = tid & 63;
    const int b16   = l & 15;
    const int g     = l >> 4;
    const int t0    = ttile * TB;

    const float* __restrict__ wih = dir ? w_ih_b : w_ih_f;
    const float* __restrict__ bi  = dir ? b_ih_b : b_ih_f;
    const float* __restrict__ bh  = dir ? b_hh_b : b_hh_f;

    short8 Bf[4][3];
    float  bias[4];
    #pragma unroll
    for (int tp = 0; tp < 4; ++tp) {
        const int n = 64 * wv + 16 * tp + b16;
        bias[tp] = (bi[n] + bh[n]) * LOG2E;
        #pragma unroll
        for (int kap = 0; kap < 3; ++kap) {
            const int f0 = 32 * kap + 8 * g;
            float f[8];
            if (f0 < FF) {
                const float4 v0 = *reinterpret_cast<const float4*>(wih + n * FF + f0);
                const float4 v1 = *reinterpret_cast<const float4*>(wih + n * FF + f0 + 4);
                f[0]=v0.x; f[1]=v0.y; f[2]=v0.z; f[3]=v0.w;
                f[4]=v1.x; f[5]=v1.y; f[6]=v1.z; f[7]=v1.w;
            } else {
                #pragma unroll
                for (int j = 0; j < 8; ++j) f[j] = 0.0f;
            }
            short8 s;
            #pragma unroll
            for (int j = 0; j < 8; ++j) s[j] = (short)f2bf(f[j] * LOG2E);
            Bf[tp][kap] = s;
        }
    }

    __shared__ __align__(16) unsigned short xa[2][CT][16][XPAD];
    for (int i = tid; i < 2 * CT * 16 * XPAD / 2; i += 256)
        reinterpret_cast<unsigned*>(&xa[0][0][0][0])[i] = 0u;
    __syncthreads();

    const int nph = TB / CT;   // 32

    {   // prologue
        const int t0p = t0;
        const int te_base = dir ? (TT - CT - t0p) : t0p;
        float2 st[20];
        #pragma unroll
        for (int q = 0; q < 20; ++q) {
            const int i = q * 256 + tid;
            const int b = i / 320, r2 = i % 320;
            const int te_rel = r2 / 40, fq = r2 % 40;
            st[q] = *reinterpret_cast<const float2*>(
                x + ((size_t)(bgrp * 16 + b) * TT + te_base + te_rel) * FF + 2 * fq);
        }
        #pragma unroll
        for (int q = 0; q < 20; ++q) {
            const int i = q * 256 + tid;
            const int b = i / 320, r2 = i % 320;
            const int te_rel = r2 / 40, fq = r2 % 40;
            const int t_off = dir ? (CT - 1 - te_rel) : te_rel;
            *reinterpret_cast<unsigned*>(&xa[0][t_off][b][2 * fq]) = packbf2(st[q].x, st[q].y);
        }
    }
    __syncthreads();

    #pragma unroll 1
    for (int ph = 0; ph < nph; ++ph) {
        const int cur = ph & 1;
        const bool have = (ph + 1) < nph;

        float2 st[20];
        if (have) {
            const int t0p = t0 + (ph + 1) * CT;
            const int te_base = dir ? (TT - CT - t0p) : t0p;
            #pragma unroll
            for (int q = 0; q < 20; ++q) {
                const int i = q * 256 + tid;
                const int b = i / 320, r2 = i % 320;
                const int te_rel = r2 / 40, fq = r2 % 40;
                st[q] = *reinterpret_cast<const float2*>(
                    x + ((size_t)(bgrp * 16 + b) * TT + te_base + te_rel) * FF + 2 * fq);
            }
        }

        #pragma unroll
        for (int t_off = 0; t_off < CT; ++t_off) {
            short8 A[3];
            #pragma unroll
            for (int kap = 0; kap < 3; ++kap)
                A[kap] = *reinterpret_cast<const short8*>(&xa[cur][t_off][b16][32 * kap + 8 * g]);
            const int t = t0 + ph * CT + t_off;
            #pragma unroll
            for (int tp = 0; tp < 4; ++tp) {
                floatx4 acc = {bias[tp], bias[tp], bias[tp], bias[tp]};
                acc = mfma16(A[0], Bf[tp][0], acc);
                acc = mfma16(A[1], Bf[tp][1], acc);
                acc = mfma16(A[2], Bf[tp][2], acc);
                const int p = (16 * tp + b16) * 4 + wv;   // unit*4 + gatetype
                #pragma unroll
                for (int r = 0; r < 4; ++r) {
                    const int bb = dir * NB + bgrp * 16 + 4 * g + r;
                    pre[((size_t)bb * TT + t) * 256 + p] = f2bf(acc[r]);
                }
            }
        }

        if (have) {
            #pragma unroll
            for (int q = 0; q < 20; ++q) {
                const int i = q * 256 + tid;
                const int b = i / 320, r2 = i % 320;
                const int te_rel = r2 / 40, fq = r2 % 40;
                const int t_off = dir ? (CT - 1 - te_rel) : te_rel;
                *reinterpret_cast<unsigned*>(&xa[cur ^ 1][t_off][b][2 * fq]) = packbf2(st[q].x, st[q].y);
            }
        }
        bar_lgkm();
    }
}

// ---------------------------------------------------------------------------
// SCAN v10 = round-13 scan (measured best, 1148 us) + ONE change:
// c2-domain cell state (c2 = 2*log2e*c) — removes the c*LOG2E mul and the
// internal s+s add from the h chain. Numerically vetted in r14/r16 passes.
// PRE stays a post-MFMA add (r16 proved C-in hurts: first MFMA would wait on
// the ring decode). Chained MFMA pair, zero-region A addressing, pointer-bump
// ring, one lgkm-only barrier per step — all byte-identical to r13.
// ---------------------------------------------------------------------------
__global__ __launch_bounds__(256, 1)
void lstm_scan_mfma7(const unsigned short* __restrict__ pre,  // [256][TT][256]
                     const float* __restrict__ w_hh_f, const float* __restrict__ w_hh_b,
                     float* __restrict__ h_out)               // [256][64]
{
    const int chain = blockIdx.x;       // dir*128 + bat
    const int dir   = chain >> 7;
    const int tid   = threadIdx.x;
    const int wv    = tid >> 6;         // unit window: 16*wv .. 16*wv+15
    const int l     = tid & 63;
    const int b16   = l & 15;           // A row / C col
    const int g4    = l >> 4;           // k-group
    const bool actC = (g4 == 0);        // C row-0 lanes (l = 0..15): cell owners
    const int  u    = 16 * wv + b16;    // this lane's unit (valid when actC)

    const float* __restrict__ whh = dir ? w_hh_b : w_hh_f;

    // B-fragments (scaled by log2e): gate gt (0:i 1:f 2:g 3:o), kap (K chunk).
    short8 Bf[4][2];
    #pragma unroll
    for (int gt = 0; gt < 4; ++gt) {
        const int n = gt * 64 + 16 * wv + b16;
        #pragma unroll
        for (int kap = 0; kap < 2; ++kap) {
            const float4 v0 = *reinterpret_cast<const float4*>(whh + n * HH + 32 * kap + 8 * g4);
            const float4 v1 = *reinterpret_cast<const float4*>(whh + n * HH + 32 * kap + 8 * g4 + 4);
            short8 s;
            s[0]=(short)f2bf(v0.x*LOG2E); s[1]=(short)f2bf(v0.y*LOG2E);
            s[2]=(short)f2bf(v0.z*LOG2E); s[3]=(short)f2bf(v0.w*LOG2E);
            s[4]=(short)f2bf(v1.x*LOG2E); s[5]=(short)f2bf(v1.y*LOG2E);
            s[6]=(short)f2bf(v1.z*LOG2E); s[7]=(short)f2bf(v1.w*LOG2E);
            Bf[gt][kap] = s;
        }
    }

    // LDS: bytes [0,128) = h buf0 (bf16[64]), [128,256) = h buf1,
    //      [256,384) = permanently-zero region (A rows 1-15 read here).
    __shared__ __align__(16) unsigned short hls[192];
    if (tid < 96) reinterpret_cast<unsigned*>(hls)[tid] = 0u;

    // PRE ring: actC lanes read uint2 = {i,f | g,o} bf16 at [chain][t][u*4].
    // 4 pre-offset pointers, each bumped +4*512B per ring cycle (no recompute).
    const uint2* __restrict__ prow = reinterpret_cast<const uint2*>(
        pre + (size_t)chain * TT * 256 + u * 4);
    uint2 prr[4] = {{0,0},{0,0},{0,0},{0,0}};
    const uint2* pp0 = prow + 4 * 64;
    const uint2* pp1 = prow + 5 * 64;
    const uint2* pp2 = prow + 6 * 64;
    const uint2* pp3 = prow + 7 * 64;
    if (actC) {
        prr[0] = prow[0 * 64];
        prr[1] = prow[1 * 64];
        prr[2] = prow[2 * 64];
        prr[3] = prow[3 * 64];
    }

    float c2 = 0.0f, h = 0.0f;   // c2 = 2*log2e * c
    __syncthreads();

    const char* lb = reinterpret_cast<const char*>(hls);
    char* lw = reinterpret_cast<char*>(hls);

    #pragma unroll 1
    for (int t = 0; t < TT; t += 4) {
        #pragma unroll
        for (int d = 0; d < 4; ++d) {
            const int cur = d & 1;       // (t+d)&1 since t%4==0

            // A fragments: row-0 lanes read h(t); others read zeros (r9/r13 layout).
            const int abase = (b16 == 0 ? 128 * cur : 256) + 16 * g4;
            const short8 A0 = *reinterpret_cast<const short8*>(lb + abase);
            const short8 A1 = *reinterpret_cast<const short8*>(lb + abase + 64);

            // capture PRE for this step, then reload ring slot (pointer bump).
            uint2 pc = prr[d];
            if (actC) {
                if (d == 0)      { prr[0] = *pp0; pp0 += 256; }
                else if (d == 1) { prr[1] = *pp1; pp1 += 256; }
                else if (d == 2) { prr[2] = *pp2; pp2 += 256; }
                else             { prr[3] = *pp3; pp3 += 256; }
            }

            // G = h @ W_hh^T (chained MFMA pair, r13 form; PRE added after —
            // r16 proved C-in puts the ring decode on the MFMA's critical path)
            const floatx4 z = {0.f, 0.f, 0.f, 0.f};
            const floatx4 ci = mfma16(A1, Bf[0][1], mfma16(A0, Bf[0][0], z));
            const floatx4 cf = mfma16(A1, Bf[1][1], mfma16(A0, Bf[1][0], z));
            const floatx4 cg = mfma16(A1, Bf[2][1], mfma16(A0, Bf[2][0], z));
            const floatx4 co = mfma16(A1, Bf[3][1], mfma16(A0, Bf[3][0], z));

            if (actC) {
                const float gi = bflo(pc.x) + ci[0];    // log2e-scaled gates
                const float gf = bfhi(pc.x) + cf[0];
                const float gg = bflo(pc.y) + cg[0];
                const float go = bfhi(pc.y) + co[0];
                const float si = sigm_s(gi);
                const float sf = sigm_s(gf);
                const float tg = tanh_s(gg);
                const float so = sigm_s(go);
                c2 = fmaf(sf, c2, K2E * (si * tg));     // c2 = 2log2e * c
                const float th = fmaf(-2.0f,
                    __builtin_amdgcn_rcpf(1.0f + __builtin_amdgcn_exp2f(c2)), 1.0f);
                h = so * th;
                *reinterpret_cast<unsigned short*>(lw + 128 * (cur ^ 1) + 2 * u) = cvt_bf16(h);
            }
            bar_lgkm();                  // LDS visibility only; ring stays in flight
        }
    }

    if (actC) h_out[(size_t)chain * HH + u] = h;
}

// ---------------------------------------------------------------------------
// Fallback: fully fused scan (round-1 kernel) if ws is too small for PRE.
// ---------------------------------------------------------------------------
__global__ __launch_bounds__(256, 1)
void lstm_scan_fused_kernel(const float* __restrict__ x,
                            const float* __restrict__ w_ih_f, const float* __restrict__ w_hh_f,
                            const float* __restrict__ b_ih_f, const float* __restrict__ b_hh_f,
                            const float* __restrict__ w_ih_b, const float* __restrict__ w_hh_b,
                            const float* __restrict__ b_ih_b, const float* __restrict__ b_hh_b,
                            float* __restrict__ h_out)
{
    const int blk = blockIdx.x;
    const int dir = blk >> 7;
    const int bat = blk & 127;
    const int tid = threadIdx.x;
    const int wv  = tid >> 6;
    const int ln  = tid & 63;

    const float* __restrict__ w_ih = dir ? w_ih_b : w_ih_f;
    const float* __restrict__ w_hh = dir ? w_hh_b : w_hh_f;
    const float* __restrict__ b_ih = dir ? b_ih_b : b_ih_f;
    const float* __restrict__ b_hh = dir ? b_hh_b : b_hh_f;

    float wi[FF], wh[HH];
    #pragma unroll
    for (int f = 0; f < FF; ++f) wi[f] = w_ih[tid * FF + f];
    #pragma unroll
    for (int j = 0; j < HH; ++j) wh[j] = w_hh[tid * HH + j];
    const float bias = b_ih[tid] + b_hh[tid];

    __shared__ float xs[2][FF];
    __shared__ float hbuf[4][HH];
    __shared__ float gbuf[2][256];

    const float* __restrict__ xrow = x + (size_t)bat * (TT * FF);
    float c = 0.0f, hreg = 0.0f;
    hbuf[wv][ln] = 0.0f;

    float xA = 0.0f;
    if (tid < FF) {
        xs[0][tid] = xrow[(size_t)(dir ? (TT - 1) : 0) * FF + tid];
        xA         = xrow[(size_t)(dir ? (TT - 2) : 1) * FF + tid];
    }
    __syncthreads();

    #pragma unroll 1
    for (int t = 0; t < TT; ++t) {
        const int cur = t & 1, nxt = cur ^ 1;
        float a0 = 0.f, a1 = 0.f, a2 = 0.f, a3 = 0.f;
        const float4* xs4 = reinterpret_cast<const float4*>(xs[cur]);
        #pragma unroll
        for (int f = 0; f < FF / 4; ++f) {
            float4 v = xs4[f];
            a0 = fmaf(wi[4*f+0], v.x, a0);
            a1 = fmaf(wi[4*f+1], v.y, a1);
            a2 = fmaf(wi[4*f+2], v.z, a2);
            a3 = fmaf(wi[4*f+3], v.w, a3);
        }
        const float4* hb4 = reinterpret_cast<const float4*>(hbuf[wv]);
        #pragma unroll
        for (int j = 0; j < HH / 4; ++j) {
            float4 v = hb4[j];
            a0 = fmaf(wh[4*j+0], v.x, a0);
            a1 = fmaf(wh[4*j+1], v.y, a1);
            a2 = fmaf(wh[4*j+2], v.z, a2);
            a3 = fmaf(wh[4*j+3], v.w, a3);
        }
        gbuf[cur][tid] = ((a0 + a1) + (a2 + a3)) + bias;

        if (tid < FF) {
            if (t + 1 < TT) xs[nxt][tid] = xA;
            if (t + 2 < TT) xA = xrow[(size_t)(dir ? (TT - 3 - t) : (t + 2)) * FF + tid];
        }
        __syncthreads();

        const float gi = gbuf[cur][ln];
        const float gf = gbuf[cur][64 + ln];
        const float gg = gbuf[cur][128 + ln];
        const float go = gbuf[cur][192 + ln];
        c    = sigm(gf) * c + sigm(gi) * tanh_f(gg);
        hreg = sigm(go) * tanh_f(c);
        hbuf[wv][ln] = hreg;
    }

    if (tid < HH) h_out[(size_t)(dir * 128 + bat) * HH + tid] = hreg;
}

__global__ __launch_bounds__(64, 1)
void fc_kernel(const float* __restrict__ h_out,   // [2][NB][HH]
               const float* __restrict__ w_fc,    // [8][128]
               const float* __restrict__ b_fc,    // [8]
               float* __restrict__ out)           // [NB][8]
{
    const int b = blockIdx.x;
    const int o = threadIdx.x;
    if (o < 8) {
        float acc = b_fc[o];
        #pragma unroll 4
        for (int j = 0; j < HH; ++j)
            acc = fmaf(h_out[(size_t)b * HH + j], w_fc[o * 128 + j], acc);
        #pragma unroll 4
        for (int j = 0; j < HH; ++j)
            acc = fmaf(h_out[(size_t)(NB + b) * HH + j], w_fc[o * 128 + 64 + j], acc);
        out[b * 8 + o] = acc;
    }
}

extern "C" void kernel_launch(void* const* d_in, const int* in_sizes, int n_in,
                              void* d_out, int out_size, void* d_ws, size_t ws_size,
                              hipStream_t stream) {
    const float* x      = (const float*)d_in[0];
    const float* w_ih_f = (const float*)d_in[2];
    const float* w_hh_f = (const float*)d_in[3];
    const float* b_ih_f = (const float*)d_in[4];
    const float* b_hh_f = (const float*)d_in[5];
    const float* w_ih_b = (const float*)d_in[6];
    const float* w_hh_b = (const float*)d_in[7];
    const float* b_ih_b = (const float*)d_in[8];
    const float* b_hh_b = (const float*)d_in[9];
    const float* w_fc   = (const float*)d_in[10];
    const float* b_fc   = (const float*)d_in[11];
    float* out = (float*)d_out;

    const size_t pre_bytes = (size_t)2 * NB * TT * 256 * 2;   // 512 MiB bf16
    const size_t need      = pre_bytes + 64 * 1024;

    if (ws_size >= need) {
        unsigned short* pre = (unsigned short*)d_ws;
        float* h_out = (float*)((char*)d_ws + pre_bytes);
        lstm_proj_mfma<<<dim3(256), dim3(256), 0, stream>>>(
            x, w_ih_f, b_ih_f, b_hh_f, w_ih_b, b_ih_b, b_hh_b, pre);
        lstm_scan_mfma7<<<dim3(256), dim3(256), 0, stream>>>(
            pre, w_hh_f, w_hh_b, h_out);
        fc_kernel<<<dim3(128), dim3(64), 0, stream>>>(h_out, w_fc, b_fc, out);
    } else {
        float* h_out = (float*)d_ws;   // 64 KiB
        lstm_scan_fused_kernel<<<dim3(256), dim3(256), 0, stream>>>(
            x, w_ih_f, w_hh_f, b_ih_f, b_hh_f,
            w_ih_b, w_hh_b, b_ih_b, b_hh_b, h_out);
        fc_kernel<<<dim3(128), dim3(64), 0, stream>>>(h_out, w_fc, b_fc, out);
    }
}